// Round 3
// baseline (628.740 us; speedup 1.0000x reference)
//
#include <hip/hip_runtime.h>
#include <stdint.h>
#include <stdio.h>

#define B_   2
#define T_   1024
#define C_   1024
#define H_   4096
#define ER_  8
#define ES_  2
#define NTOK (B_*T_)   // 2048

typedef __attribute__((ext_vector_type(4))) float  f32x4;
typedef __attribute__((ext_vector_type(8))) __bf16 bf16x8;

__device__ __forceinline__ unsigned short f2bf(float f) {
  unsigned u = __builtin_bit_cast(unsigned, f);
  u += 0x7FFFu + ((u >> 16) & 1u);          // RNE
  return (unsigned short)(u >> 16);
}

__device__ __forceinline__ void async_ld16(void* lds, const void* g) {
  __builtin_amdgcn_global_load_lds(
      (const __attribute__((address_space(1))) char*)(uintptr_t)g,
      (__attribute__((address_space(3))) char*)(uintptr_t)lds, 16, 0, 0);
}

__device__ __forceinline__ f32x4 mfma16(bf16x8 a, bf16x8 b, f32x4 c) {
  return __builtin_amdgcn_mfma_f32_16x16x32_bf16(a, b, c, 0, 0, 0);
}

// ---------------------------------------------------------------- init out = u
__global__ void k_init(const float* __restrict__ u, float* __restrict__ out) {
  size_t i = (size_t)blockIdx.x * 256 + threadIdx.x;
  reinterpret_cast<float4*>(out)[i] = reinterpret_cast<const float4*>(u)[i];
}

// -------------------------------------------- per-token norm scales + routing
__global__ void k_prep(const float* __restrict__ u, const float* __restrict__ gs,
                       const float* __restrict__ gr, const float* __restrict__ cent,
                       __bf16* __restrict__ xns, __bf16* __restrict__ xnr,
                       int* __restrict__ tki, float* __restrict__ tkg)
{
  const int t = blockIdx.x, tid = threadIdx.x;
  float4 v = reinterpret_cast<const float4*>(u + (size_t)t * C_)[tid];
  float ss = v.x*v.x + v.y*v.y + v.z*v.z + v.w*v.w;
  const int c0 = tid * 4;
  float sc[ER_];
  #pragma unroll
  for (int e = 0; e < ER_; ++e) {
    sc[e] = v.x * cent[(c0+0)*ER_ + e] + v.y * cent[(c0+1)*ER_ + e]
          + v.z * cent[(c0+2)*ER_ + e] + v.w * cent[(c0+3)*ER_ + e];
  }
  #pragma unroll
  for (int o = 32; o > 0; o >>= 1) {
    ss += __shfl_down(ss, o);
    #pragma unroll
    for (int e = 0; e < ER_; ++e) sc[e] += __shfl_down(sc[e], o);
  }
  __shared__ float red[4][ER_ + 1];
  __shared__ float sbc;
  const int w = tid >> 6;
  if ((tid & 63) == 0) {
    red[w][0] = ss;
    #pragma unroll
    for (int e = 0; e < ER_; ++e) red[w][1 + e] = sc[e];
  }
  __syncthreads();
  if (tid == 0) {
    float S = red[0][0] + red[1][0] + red[2][0] + red[3][0];
    sbc = rsqrtf(S * (1.0f / C_) + 1.1920929e-07f);
    float p[ER_]; float psum = 0.f;
    #pragma unroll
    for (int e = 0; e < ER_; ++e) {
      float d = red[0][1+e] + red[1][1+e] + red[2][1+e] + red[3][1+e];
      p[e] = 1.f / (1.f + expf(-d));
      psum += p[e];
    }
    int i0 = 0;
    for (int e = 1; e < ER_; ++e) if (p[e] > p[i0]) i0 = e;
    int i1 = -1;
    for (int e = 0; e < ER_; ++e) { if (e == i0) continue; if (i1 < 0 || p[e] > p[i1]) i1 = e; }
    tki[t*2+0] = i0;  tki[t*2+1] = i1;
    tkg[t*2+0] = p[i0] / psum;  tkg[t*2+1] = p[i1] / psum;
  }
  __syncthreads();
  const float s = sbc;
  ushort4 os, orr;
  os.x  = f2bf(v.x * s * gs[c0+0]); os.y  = f2bf(v.y * s * gs[c0+1]);
  os.z  = f2bf(v.z * s * gs[c0+2]); os.w  = f2bf(v.w * s * gs[c0+3]);
  orr.x = f2bf(v.x * s * gr[c0+0]); orr.y = f2bf(v.y * s * gr[c0+1]);
  orr.z = f2bf(v.z * s * gr[c0+2]); orr.w = f2bf(v.w * s * gr[c0+3]);
  reinterpret_cast<ushort4*>(xns)[(size_t)t * (C_/4) + tid] = os;
  reinterpret_cast<ushort4*>(xnr)[(size_t)t * (C_/4) + tid] = orr;
}

// -------------------------------------------------- expert token-list builder
__global__ void k_build(const int* __restrict__ tki, const float* __restrict__ tkg,
                        int* __restrict__ listTok, float* __restrict__ listGate,
                        int* __restrict__ offs, int* __restrict__ cnts)
{
  __shared__ int cnt[ER_], cur[ER_], off[ER_];
  const int tid = threadIdx.x;
  if (tid < ER_) cnt[tid] = 0;
  __syncthreads();
  for (int i = tid; i < NTOK*2; i += 256) atomicAdd(&cnt[tki[i]], 1);
  __syncthreads();
  if (tid == 0) {
    int a = 0;
    for (int e = 0; e < ER_; ++e) { off[e] = a; cur[e] = a; a += cnt[e]; }
  }
  __syncthreads();
  for (int i = tid; i < NTOK*2; i += 256) {
    int e = tki[i];
    int p = atomicAdd(&cur[e], 1);
    listTok[p]  = i >> 1;
    listGate[p] = tkg[i];
  }
  if (tid < ER_) { offs[tid] = off[tid]; cnts[tid] = cnt[tid]; }
}

// --------------------------------- weight transpose + fp32->bf16 ([K][N]->[N][K])
__global__ void k_convT(const float* __restrict__ src, __bf16* __restrict__ dst,
                        int K, int N)
{
  const int e = blockIdx.z;
  src += (size_t)e * K * N;
  unsigned short* d = reinterpret_cast<unsigned short*>(dst) + (size_t)e * K * N;
  const int n0 = blockIdx.x * 64, k0 = blockIdx.y * 64;
  __shared__ float tb[64][65];
  const int tid = threadIdx.x;
  const int r = tid >> 4, c = (tid & 15) * 4;
  #pragma unroll
  for (int rr = r; rr < 64; rr += 16) {
    float4 v = *reinterpret_cast<const float4*>(&src[(size_t)(k0+rr)*N + n0 + c]);
    tb[rr][c] = v.x; tb[rr][c+1] = v.y; tb[rr][c+2] = v.z; tb[rr][c+3] = v.w;
  }
  __syncthreads();
  #pragma unroll
  for (int rr = r; rr < 64; rr += 16) {
    ushort4 o;
    o.x = f2bf(tb[c+0][rr]); o.y = f2bf(tb[c+1][rr]);
    o.z = f2bf(tb[c+2][rr]); o.w = f2bf(tb[c+3][rr]);
    *reinterpret_cast<ushort4*>(&d[(size_t)(n0+rr)*K + k0 + c]) = o;
  }
}

// ------------------------------------------------------------- tiled bf16 GEMM
// BM=256 x BN=128 tile, BK=32, 8 waves (4x2), 512 threads, 16x16x32 MFMA.
// 3-deep LDS pipeline, raw s_barrier + counted vmcnt(3) (T3+T4 minimal form).
// LDS XOR involution swizzle on 16B chunks (rule 21: source + read, same XOR).
// MODE 0: dense, hid = gelu(A*Wt + b1)                 (shared gemm1, N=2H)
// MODE 1: gathered A, hid = gelu(A*Wt + b1)            (routed gemm1)
// MODE 2: dense, out += A*Wt (+b2 at kc==0) atomically (shared gemm2, split-K)
// MODE 3: slot A, out += gate*(A*Wt + b2) atomically   (routed gemm2, split-K)
template<int KDIM, int KCHUNK, int NDIM, int KS, int MODE>
__global__ __launch_bounds__(512, 4)
void k_gemm(const __bf16* __restrict__ Abase, const __bf16* __restrict__ Wt,
            const float* __restrict__ bias, __bf16* __restrict__ hid,
            float* __restrict__ out,
            const int* __restrict__ listTok, const float* __restrict__ listGate,
            const int* __restrict__ offs, const int* __restrict__ cnts)
{
  constexpr int NT = KCHUNK / 32;
  constexpr bool ROUTED = (MODE == 1 || MODE == 3);
  const int z = blockIdx.z;
  const int e  = z / KS;
  const int kc = z % KS;
  const int kbase = kc * KCHUNK;

  int M, slotbase;
  if (ROUTED) { M = cnts[e]; slotbase = offs[e]; }
  else        { M = NTOK;    slotbase = 0; }

  // XCD-chunked bijective swizzle, m fastest (blocks sharing a W n-panel
  // land contiguously on one XCD).
  const int Mx = gridDim.y;
  const int lin = blockIdx.x * Mx + blockIdx.y;
  const int nblk = gridDim.x * Mx;
  const int q = nblk >> 3, rm = nblk & 7;
  const int xcd = lin & 7, idx = lin >> 3;
  const int swz = (xcd < rm ? xcd * (q + 1) : rm * (q + 1) + (xcd - rm) * q) + idx;
  const int m0 = (swz % Mx) * 256;
  if (m0 >= M) return;
  const int n0 = (swz / Mx) * 128;

  const int tid = threadIdx.x;

  __shared__ __align__(16) __bf16 Al[3][256 * 32];
  __shared__ __align__(16) __bf16 Bl[3][128 * 32];

  // ---- staging addresses (swizzled source chunk) ----
  const int sr = tid >> 2;                                  // 0..127
  const int csrc = ((tid & 3) ^ ((sr >> 1) & 3)) * 8;       // elems, XOR involution
  int r0 = m0 + sr;        if (r0 >= M) r0 = M - 1;
  int r1 = m0 + 128 + sr;  if (r1 >= M) r1 = M - 1;
  size_t arow0, arow1;
  if (MODE == 1)      { arow0 = (size_t)listTok[slotbase + r0]; arow1 = (size_t)listTok[slotbase + r1]; }
  else if (MODE == 3) { arow0 = (size_t)(slotbase + r0);        arow1 = (size_t)(slotbase + r1); }
  else                { arow0 = (size_t)r0;                     arow1 = (size_t)r1; }
  const __bf16* ga0 = Abase + arow0 * KDIM + kbase + csrc;
  const __bf16* ga1 = Abase + arow1 * KDIM + kbase + csrc;
  const __bf16* gb0 = Wt + ((size_t)e * NDIM + n0 + sr) * KDIM + kbase + csrc;
  const unsigned wofs = (tid >> 6) * 1024;                  // per-wave 1KB slot

  char* AlB = (char*)Al;
  char* BlB = (char*)Bl;
  auto stage = [&](int buf, int t) {
    char* ab = AlB + buf * 16384 + wofs;
    async_ld16(ab,        ga0 + t * 32);
    async_ld16(ab + 8192, ga1 + t * 32);
    char* bb = BlB + buf * 8192 + wofs;
    async_ld16(bb, gb0 + t * 32);
  };

  // ---- fragment read offsets ----
  const int w = tid >> 6, l = tid & 63;
  const int wm = (w >> 1) * 64;            // wave row block (0..3)*64
  const int wc = (w & 1) * 64;             // wave col block
  const int lrow = l & 15;
  const int kq = ((l >> 4) ^ ((l >> 1) & 3)) * 8;

  f32x4 acc[4][4];
  #pragma unroll
  for (int m = 0; m < 4; ++m)
    #pragma unroll
    for (int n = 0; n < 4; ++n) acc[m][n] = (f32x4){0.f, 0.f, 0.f, 0.f};

  auto compute = [&](int buf) {
    bf16x8 af[4], bfr[4];
    #pragma unroll
    for (int m = 0; m < 4; ++m)
      af[m] = *reinterpret_cast<const bf16x8*>(&Al[buf][(wm + m*16 + lrow)*32 + kq]);
    #pragma unroll
    for (int n = 0; n < 4; ++n)
      bfr[n] = *reinterpret_cast<const bf16x8*>(&Bl[buf][(wc + n*16 + lrow)*32 + kq]);
    __builtin_amdgcn_s_setprio(1);
    #pragma unroll
    for (int m = 0; m < 4; ++m)
      #pragma unroll
      for (int n = 0; n < 4; ++n)
        acc[m][n] = mfma16(af[m], bfr[n], acc[m][n]);
    __builtin_amdgcn_s_setprio(0);
  };

  // ---- pipelined K-loop: 2 stages in flight across barriers ----
  stage(0, 0);
  stage(1, 1);
  for (int t = 0; t < NT; ++t) {
    if (t + 1 < NT) asm volatile("s_waitcnt vmcnt(3)" ::: "memory");
    else            asm volatile("s_waitcnt vmcnt(0)" ::: "memory");
    __builtin_amdgcn_s_barrier();
    __builtin_amdgcn_sched_barrier(0);
    if (t + 2 < NT) stage((t + 2) % 3, t + 2);
    compute(t % 3);
  }

  // ---- epilogue — C/D layout: col = lane&15, row = (lane>>4)*4 + reg ----
  #pragma unroll
  for (int m = 0; m < 4; ++m) {
    const int rbase = m0 + wm + m*16 + (l >> 4) * 4;
    #pragma unroll
    for (int rg = 0; rg < 4; ++rg) {
      const int r = rbase + rg;
      if (r >= M) continue;
      if constexpr (MODE == 0) {
        #pragma unroll
        for (int n = 0; n < 4; ++n) {
          const int col = n0 + wc + n*16 + lrow;
          float v = acc[m][n][rg] + bias[col];
          v = 0.5f * v * (1.0f + erff(v * 0.70710678118654752f));
          __builtin_nontemporal_store(f2bf(v),
              reinterpret_cast<unsigned short*>(hid) + (size_t)r * NDIM + col);
        }
      } else if constexpr (MODE == 1) {
        #pragma unroll
        for (int n = 0; n < 4; ++n) {
          const int col = n0 + wc + n*16 + lrow;
          float v = acc[m][n][rg] + bias[e * NDIM + col];
          v = 0.5f * v * (1.0f + erff(v * 0.70710678118654752f));
          __builtin_nontemporal_store(f2bf(v),
              reinterpret_cast<unsigned short*>(hid) + (size_t)(slotbase + r) * NDIM + col);
        }
      } else if constexpr (MODE == 2) {
        #pragma unroll
        for (int n = 0; n < 4; ++n) {
          const int col = n0 + wc + n*16 + lrow;
          float v = acc[m][n][rg] + (kc == 0 ? bias[col] + bias[C_ + col] : 0.f);
          unsafeAtomicAdd(&out[(size_t)r * C_ + col], v);
        }
      } else {
        const int tok = listTok[slotbase + r];
        const float g = listGate[slotbase + r];
        #pragma unroll
        for (int n = 0; n < 4; ++n) {
          const int col = n0 + wc + n*16 + lrow;
          float v = acc[m][n][rg] + (kc == 0 ? bias[e * C_ + col] : 0.f);
          unsafeAtomicAdd(&out[(size_t)tok * C_ + col], g * v);
        }
      }
    }
  }
}

// -----------------------------------------------------------------------------
extern "C" void kernel_launch(void* const* d_in, const int* in_sizes, int n_in,
                              void* d_out, int out_size, void* d_ws, size_t ws_size,
                              hipStream_t stream)
{
  const float* u    = (const float*)d_in[0];
  const float* gs   = (const float*)d_in[1];
  const float* W1s  = (const float*)d_in[2];
  const float* b1s  = (const float*)d_in[3];
  const float* W2s  = (const float*)d_in[4];
  const float* b2s  = (const float*)d_in[5];
  const float* gr   = (const float*)d_in[6];
  const float* W1r  = (const float*)d_in[7];
  const float* b1r  = (const float*)d_in[8];
  const float* W2r  = (const float*)d_in[9];
  const float* b2r  = (const float*)d_in[10];
  const float* cent = (const float*)d_in[11];
  float* out = (float*)d_out;

  char* ws = (char*)d_ws;
  size_t off = 0;
  auto alloc = [&](size_t bytes) -> char* {
    char* p = ws + off;
    off += (bytes + 255) & ~(size_t)255;
    return p;
  };
  __bf16* wbuf = (__bf16*)alloc((size_t)(ES_ + ER_) * H_ * C_ * 2);  // 84 MB, reused W1t->W2t
  __bf16* xns  = (__bf16*)alloc((size_t)NTOK * C_ * 2);
  __bf16* xnr  = (__bf16*)alloc((size_t)NTOK * C_ * 2);
  __bf16* hids = (__bf16*)alloc((size_t)NTOK * (ES_*H_) * 2);        // [2048][8192] bf16
  __bf16* hidr = (__bf16*)alloc((size_t)NTOK * 2 * H_ * 2);          // [4096 slots][4096]
  int*    tki      = (int*)  alloc(NTOK * 2 * 4);
  float*  tkg      = (float*)alloc(NTOK * 2 * 4);
  int*    listTok  = (int*)  alloc(NTOK * 2 * 4);
  float*  listGate = (float*)alloc(NTOK * 2 * 4);
  int*    offs     = (int*)  alloc(64);
  int*    cnts     = (int*)  alloc(64);
  if (off > ws_size) {
    fprintf(stderr, "ATHENA: WORKSPACE TOO SMALL: need %zu bytes, have %zu\n", off, ws_size);
    return;
  }

  __bf16* wt_s = wbuf;                       // shared experts (stacked)
  __bf16* wt_r = wbuf + (size_t)ES_ * H_ * C_;

  k_init<<<dim3(NTOK * C_ / 1024), dim3(256), 0, stream>>>(u, out);
  k_prep<<<dim3(NTOK), dim3(256), 0, stream>>>(u, gs, gr, cent, xns, xnr, tki, tkg);
  k_build<<<dim3(1), dim3(256), 0, stream>>>(tki, tkg, listTok, listGate, offs, cnts);

  // W1 [E][C][H] -> bf16 [E*H][C]
  k_convT<<<dim3(H_/64, C_/64, ES_), dim3(256), 0, stream>>>(W1s, wt_s, C_, H_);
  k_convT<<<dim3(H_/64, C_/64, ER_), dim3(256), 0, stream>>>(W1r, wt_r, C_, H_);

  // shared gemm1: dense [2048,1024] x [8192,1024]^T -> hids [2048][8192]
  k_gemm<C_, C_, ES_*H_, 1, 0><<<dim3(64, 8, 1), dim3(512), 0, stream>>>(
      xns, wt_s, b1s, hids, nullptr, nullptr, nullptr, nullptr, nullptr);
  // routed gemm1: grouped, slots -> hidr
  k_gemm<C_, C_, H_, 1, 1><<<dim3(32, 8, ER_), dim3(512), 0, stream>>>(
      xnr, wt_r, b1r, hidr, nullptr, listTok, listGate, offs, cnts);

  // W2: shared stacked [2H][C] -> [C][2H]; routed per-expert [H][C] -> [C][H]
  k_convT<<<dim3(C_/64, (ES_*H_)/64, 1), dim3(256), 0, stream>>>(W2s, wt_s, ES_*H_, C_);
  k_convT<<<dim3(C_/64, H_/64, ER_), dim3(256), 0, stream>>>(W2r, wt_r, H_, C_);

  // shared gemm2: out += hids x wt_s + b2 (split-K 4, atomic)
  k_gemm<ES_*H_, 2048, C_, 4, 2><<<dim3(8, 8, 4), dim3(512), 0, stream>>>(
      hids, wt_s, b2s, nullptr, out, nullptr, nullptr, nullptr, nullptr);
  // routed gemm2: out += gate*(hidr x wt_r + b2) (split-K 2, atomic)
  k_gemm<H_, 2048, C_, 2, 3><<<dim3(8, 8, ER_*2), dim3(512), 0, stream>>>(
      hidr, wt_r, b2r, nullptr, out, listTok, listGate, offs, cnts);
}

// Round 4
// 583.973 us; speedup vs baseline: 1.0767x; 1.0767x over previous
//
#include <hip/hip_runtime.h>
#include <stdint.h>
#include <stdio.h>

#define B_   2
#define T_   1024
#define C_   1024
#define H_   4096
#define ER_  8
#define ES_  2
#define NTOK (B_*T_)   // 2048

typedef __attribute__((ext_vector_type(4))) float  f32x4;
typedef __attribute__((ext_vector_type(8))) __bf16 bf16x8;
typedef __attribute__((ext_vector_type(8))) unsigned short us8;

__device__ __forceinline__ unsigned short f2bf(float f) {
  unsigned u = __builtin_bit_cast(unsigned, f);
  u += 0x7FFFu + ((u >> 16) & 1u);          // RNE
  return (unsigned short)(u >> 16);
}

__device__ __forceinline__ void async_ld16(void* lds, const void* g) {
  __builtin_amdgcn_global_load_lds(
      (const __attribute__((address_space(1))) char*)(uintptr_t)g,
      (__attribute__((address_space(3))) char*)(uintptr_t)lds, 16, 0, 0);
}

__device__ __forceinline__ f32x4 mfma16(bf16x8 a, bf16x8 b, f32x4 c) {
  return __builtin_amdgcn_mfma_f32_16x16x32_bf16(a, b, c, 0, 0, 0);
}

// ---------------------------------------------------------------- init out = u
__global__ void k_init(const float* __restrict__ u, float* __restrict__ out) {
  size_t i = (size_t)blockIdx.x * 256 + threadIdx.x;
  reinterpret_cast<float4*>(out)[i] = reinterpret_cast<const float4*>(u)[i];
}

// -------------------------------------------- per-token norm scales + routing
__global__ void k_prep(const float* __restrict__ u, const float* __restrict__ gs,
                       const float* __restrict__ gr, const float* __restrict__ cent,
                       __bf16* __restrict__ xns, __bf16* __restrict__ xnr,
                       int* __restrict__ tki, float* __restrict__ tkg)
{
  const int t = blockIdx.x, tid = threadIdx.x;
  float4 v = reinterpret_cast<const float4*>(u + (size_t)t * C_)[tid];
  float ss = v.x*v.x + v.y*v.y + v.z*v.z + v.w*v.w;
  const int c0 = tid * 4;
  float sc[ER_];
  #pragma unroll
  for (int e = 0; e < ER_; ++e) {
    sc[e] = v.x * cent[(c0+0)*ER_ + e] + v.y * cent[(c0+1)*ER_ + e]
          + v.z * cent[(c0+2)*ER_ + e] + v.w * cent[(c0+3)*ER_ + e];
  }
  #pragma unroll
  for (int o = 32; o > 0; o >>= 1) {
    ss += __shfl_down(ss, o);
    #pragma unroll
    for (int e = 0; e < ER_; ++e) sc[e] += __shfl_down(sc[e], o);
  }
  __shared__ float red[4][ER_ + 1];
  __shared__ float sbc;
  const int w = tid >> 6;
  if ((tid & 63) == 0) {
    red[w][0] = ss;
    #pragma unroll
    for (int e = 0; e < ER_; ++e) red[w][1 + e] = sc[e];
  }
  __syncthreads();
  if (tid == 0) {
    float S = red[0][0] + red[1][0] + red[2][0] + red[3][0];
    sbc = rsqrtf(S * (1.0f / C_) + 1.1920929e-07f);
    float p[ER_]; float psum = 0.f;
    #pragma unroll
    for (int e = 0; e < ER_; ++e) {
      float d = red[0][1+e] + red[1][1+e] + red[2][1+e] + red[3][1+e];
      p[e] = 1.f / (1.f + expf(-d));
      psum += p[e];
    }
    int i0 = 0;
    for (int e = 1; e < ER_; ++e) if (p[e] > p[i0]) i0 = e;
    int i1 = -1;
    for (int e = 0; e < ER_; ++e) { if (e == i0) continue; if (i1 < 0 || p[e] > p[i1]) i1 = e; }
    tki[t*2+0] = i0;  tki[t*2+1] = i1;
    tkg[t*2+0] = p[i0] / psum;  tkg[t*2+1] = p[i1] / psum;
  }
  __syncthreads();
  const float s = sbc;
  ushort4 os, orr;
  os.x  = f2bf(v.x * s * gs[c0+0]); os.y  = f2bf(v.y * s * gs[c0+1]);
  os.z  = f2bf(v.z * s * gs[c0+2]); os.w  = f2bf(v.w * s * gs[c0+3]);
  orr.x = f2bf(v.x * s * gr[c0+0]); orr.y = f2bf(v.y * s * gr[c0+1]);
  orr.z = f2bf(v.z * s * gr[c0+2]); orr.w = f2bf(v.w * s * gr[c0+3]);
  reinterpret_cast<ushort4*>(xns)[(size_t)t * (C_/4) + tid] = os;
  reinterpret_cast<ushort4*>(xnr)[(size_t)t * (C_/4) + tid] = orr;
}

// -------------------------------------------------- expert token-list builder
__global__ void k_build(const int* __restrict__ tki, const float* __restrict__ tkg,
                        int* __restrict__ listTok, float* __restrict__ listGate,
                        int* __restrict__ offs, int* __restrict__ cnts)
{
  __shared__ int cnt[ER_], cur[ER_], off[ER_];
  const int tid = threadIdx.x;
  if (tid < ER_) cnt[tid] = 0;
  __syncthreads();
  for (int i = tid; i < NTOK*2; i += 256) atomicAdd(&cnt[tki[i]], 1);
  __syncthreads();
  if (tid == 0) {
    int a = 0;
    for (int e = 0; e < ER_; ++e) { off[e] = a; cur[e] = a; a += cnt[e]; }
  }
  __syncthreads();
  for (int i = tid; i < NTOK*2; i += 256) {
    int e = tki[i];
    int p = atomicAdd(&cur[e], 1);
    listTok[p]  = i >> 1;
    listGate[p] = tkg[i];
  }
  if (tid < ER_) { offs[tid] = off[tid]; cnts[tid] = cnt[tid]; }
}

// ---------------- weight transpose + fp32->bf16 ([K][N] -> [N][K]), bf16 LDS
__global__ void k_convT(const float* __restrict__ src, __bf16* __restrict__ dst,
                        int K, int N)
{
  const int e = blockIdx.z;
  src += (size_t)e * K * N;
  unsigned short* d = reinterpret_cast<unsigned short*>(dst) + (size_t)e * K * N;
  const int n0 = blockIdx.x * 64, k0 = blockIdx.y * 64;
  __shared__ unsigned short tb[64][72];
  const int tid = threadIdx.x;
  const int kr = tid >> 4, c4 = (tid & 15) * 4;
  #pragma unroll
  for (int i = 0; i < 4; ++i) {
    const int kk = kr + i * 16;
    float4 v = *reinterpret_cast<const float4*>(&src[(size_t)(k0+kk)*N + n0 + c4]);
    tb[kk][c4+0] = f2bf(v.x); tb[kk][c4+1] = f2bf(v.y);
    tb[kk][c4+2] = f2bf(v.z); tb[kk][c4+3] = f2bf(v.w);
  }
  __syncthreads();
  const int nr = tid >> 2;
  #pragma unroll
  for (int j = 0; j < 2; ++j) {
    const int kc = ((tid & 3) + j * 4) * 8;
    us8 o;
    #pragma unroll
    for (int t2 = 0; t2 < 8; ++t2) o[t2] = tb[kc + t2][nr];
    *reinterpret_cast<us8*>(&d[(size_t)(n0+nr)*K + k0 + kc]) = o;
  }
}

// ------------------------------------------------------------- fused GEMM
// 128x128 tile, BK=64, 4 waves (2x2), 256 threads, single-buffered 32KB LDS,
// m97 2-barrier convoy loop; occupancy (3 blocks/CU) provides the overlap.
// T2 XOR involution swizzle on 16B chunks: source chunk and ds_read chunk
// both XORed with (row&7) (rule 21), LDS dest stays linear.
// PHASE 1 (z groups): z<2  shared expert z: dense A=xns -> hids cols z*H
//                     z>=2 routed e=z-2: gathered A=xnr -> hidr slots
// PHASE 2 (z groups): z<2  shared kc=z (K=8192 split 2): A=hids, out += .. (atomic)
//                     z>=2 routed (e,kc)=((z-2)>>1,(z-2)&1): A=hidr slots, atomic
struct GP {
  const __bf16 *xns, *xnr, *hids, *hidr, *wts, *wtr;
  const float *b1s, *b1r, *b2s, *b2r;
  __bf16 *hidws, *hidwr;
  float* out;
  const int* listTok; const float* listGate; const int* offs; const int* cnts;
};

template<int PHASE>
__global__ __launch_bounds__(256, 3)
void k_gemm(GP p)
{
  const int z = blockIdx.z;
  int M, slotbase = 0, kbase = 0, NT, rowmode;   // rowmode 0=dense 1=listTok 2=slot
  long KD;
  const __bf16 *Ab, *Wb;
  const float* bias;
  __bf16* hb = nullptr; int hstride = 0;
  int eidx = 0;

  if (PHASE == 1) {
    KD = C_; NT = C_ / 64;
    if (z < ES_) {
      M = NTOK; rowmode = 0; Ab = p.xns;
      Wb = p.wts + (size_t)z * H_ * C_;
      bias = p.b1s + z * H_;
      hb = p.hidws + z * H_; hstride = ES_ * H_;
    } else {
      eidx = z - ES_;
      M = p.cnts[eidx]; slotbase = p.offs[eidx]; rowmode = 1; Ab = p.xnr;
      Wb = p.wtr + (size_t)eidx * H_ * C_;
      bias = p.b1r + eidx * H_;
      hb = p.hidwr + (size_t)slotbase * H_; hstride = H_;
    }
  } else {
    if (z < 2) {
      const int kc = z;
      M = NTOK; rowmode = 0; Ab = p.hids; KD = ES_ * H_;
      kbase = kc * 4096; NT = 4096 / 64;
      Wb = p.wts; bias = (kc == 0) ? p.b2s : nullptr;
    } else {
      const int zz = z - 2;
      eidx = zz >> 1; const int kc = zz & 1;
      M = p.cnts[eidx]; slotbase = p.offs[eidx]; rowmode = 2; Ab = p.hidr; KD = H_;
      kbase = kc * 2048; NT = 2048 / 64;
      Wb = p.wtr + (size_t)eidx * C_ * H_;
      bias = (kc == 0) ? (p.b2r + eidx * C_) : nullptr;
    }
  }

  // XCD-chunked bijective swizzle over (n,m), m fastest within a chunk
  const int Mx = gridDim.y;
  const int lin = blockIdx.x * Mx + blockIdx.y;
  const int nblk = gridDim.x * Mx;
  const int q = nblk >> 3, rm = nblk & 7;
  const int xcd = lin & 7, idx = lin >> 3;
  const int swz = (xcd < rm ? xcd * (q + 1) : rm * (q + 1) + (xcd - rm) * q) + idx;
  const int m0 = (swz % Mx) * 128;
  if (m0 >= M) return;
  const int n0 = (swz / Mx) * 128;

  const int tid = threadIdx.x;
  const int w = tid >> 6, l = tid & 63;

  __shared__ __align__(16) __bf16 Al[128 * 64];
  __shared__ __align__(16) __bf16 Bl[128 * 64];

  // ---- staging addresses: instr i covers row i*32 + (tid>>3), chunk tid&7 ----
  const int srow = tid >> 3;                       // 0..31
  const int cs = ((tid & 7) ^ (srow & 7)) * 8;     // swizzled source chunk (elems)
  const __bf16* aptr[4];
  const __bf16* bptr[4];
  #pragma unroll
  for (int i = 0; i < 4; ++i) {
    int rr = i * 32 + srow;
    int ra = m0 + rr; if (ra >= M) ra = M - 1;
    size_t arow;
    if (rowmode == 0)      arow = (size_t)ra;
    else if (rowmode == 1) arow = (size_t)p.listTok[slotbase + ra];
    else                   arow = (size_t)(slotbase + ra);
    aptr[i] = Ab + arow * KD + kbase + cs;
    bptr[i] = Wb + (size_t)(n0 + rr) * KD + kbase + cs;
  }
  char* AlB = (char*)Al;
  char* BlB = (char*)Bl;
  const unsigned wofs = w * 1024;

  // ---- fragment read setup ----
  const int wm = (w >> 1) * 64, wc = (w & 1) * 64;
  const int lr = l & 15, qh = l >> 4;
  int slotk[2];
  #pragma unroll
  for (int ks = 0; ks < 2; ++ks) slotk[ks] = ((ks * 4 + qh) ^ (l & 7)) * 8;

  f32x4 acc[4][4];
  #pragma unroll
  for (int m = 0; m < 4; ++m)
    #pragma unroll
    for (int n = 0; n < 4; ++n) acc[m][n] = (f32x4){0.f, 0.f, 0.f, 0.f};

  // ---- K loop: stage -> sync -> compute -> sync (m97 convoy) ----
  for (int t = 0; t < NT; ++t) {
    const int k0 = t * 64;
    #pragma unroll
    for (int i = 0; i < 4; ++i) async_ld16(AlB + i * 4096 + wofs, aptr[i] + k0);
    #pragma unroll
    for (int i = 0; i < 4; ++i) async_ld16(BlB + i * 4096 + wofs, bptr[i] + k0);
    __syncthreads();
    #pragma unroll
    for (int ks = 0; ks < 2; ++ks) {
      bf16x8 af[4], bfr[4];
      #pragma unroll
      for (int m = 0; m < 4; ++m)
        af[m] = *reinterpret_cast<const bf16x8*>(&Al[(wm + m*16 + lr)*64 + slotk[ks]]);
      #pragma unroll
      for (int n = 0; n < 4; ++n)
        bfr[n] = *reinterpret_cast<const bf16x8*>(&Bl[(wc + n*16 + lr)*64 + slotk[ks]]);
      #pragma unroll
      for (int m = 0; m < 4; ++m)
        #pragma unroll
        for (int n = 0; n < 4; ++n)
          acc[m][n] = mfma16(af[m], bfr[n], acc[m][n]);
    }
    __syncthreads();
  }

  // ---- epilogue — C/D layout: col = lane&15, row = (lane>>4)*4 + reg ----
  #pragma unroll
  for (int m = 0; m < 4; ++m) {
    const int rbase = m0 + wm + m*16 + qh * 4;
    #pragma unroll
    for (int rg = 0; rg < 4; ++rg) {
      const int r = rbase + rg;
      if (r >= M) continue;
      if constexpr (PHASE == 1) {
        #pragma unroll
        for (int n = 0; n < 4; ++n) {
          const int col = n0 + wc + n*16 + lr;
          float v = acc[m][n][rg] + bias[col];
          v = 0.5f * v * (1.0f + erff(v * 0.70710678118654752f));
          __builtin_nontemporal_store(f2bf(v),
              reinterpret_cast<unsigned short*>(hb) + (size_t)r * hstride + col);
        }
      } else {
        int tok; float g;
        if (rowmode == 0) { tok = r; g = 1.0f; }
        else              { tok = p.listTok[slotbase + r]; g = p.listGate[slotbase + r]; }
        #pragma unroll
        for (int n = 0; n < 4; ++n) {
          const int col = n0 + wc + n*16 + lr;
          float v = acc[m][n][rg];
          if (bias) {
            if (rowmode == 0) v += p.b2s[col] + p.b2s[C_ + col];
            else              v += bias[col];
          }
          unsafeAtomicAdd(&p.out[(size_t)tok * C_ + col], g * v);
        }
      }
    }
  }
}

// -----------------------------------------------------------------------------
extern "C" void kernel_launch(void* const* d_in, const int* in_sizes, int n_in,
                              void* d_out, int out_size, void* d_ws, size_t ws_size,
                              hipStream_t stream)
{
  const float* u    = (const float*)d_in[0];
  const float* gs   = (const float*)d_in[1];
  const float* W1s  = (const float*)d_in[2];
  const float* b1s  = (const float*)d_in[3];
  const float* W2s  = (const float*)d_in[4];
  const float* b2s  = (const float*)d_in[5];
  const float* gr   = (const float*)d_in[6];
  const float* W1r  = (const float*)d_in[7];
  const float* b1r  = (const float*)d_in[8];
  const float* W2r  = (const float*)d_in[9];
  const float* b2r  = (const float*)d_in[10];
  const float* cent = (const float*)d_in[11];
  float* out = (float*)d_out;

  char* ws = (char*)d_ws;
  size_t off = 0;
  auto alloc = [&](size_t bytes) -> char* {
    char* p = ws + off;
    off += (bytes + 255) & ~(size_t)255;
    return p;
  };
  __bf16* wbuf = (__bf16*)alloc((size_t)(ES_ + ER_) * H_ * C_ * 2);  // 84 MB, reused W1t->W2t
  __bf16* xns  = (__bf16*)alloc((size_t)NTOK * C_ * 2);
  __bf16* xnr  = (__bf16*)alloc((size_t)NTOK * C_ * 2);
  __bf16* hids = (__bf16*)alloc((size_t)NTOK * (ES_*H_) * 2);        // [2048][8192]
  __bf16* hidr = (__bf16*)alloc((size_t)NTOK * 2 * H_ * 2);          // [4096][4096]
  int*    tki      = (int*)  alloc(NTOK * 2 * 4);
  float*  tkg      = (float*)alloc(NTOK * 2 * 4);
  int*    listTok  = (int*)  alloc(NTOK * 2 * 4);
  float*  listGate = (float*)alloc(NTOK * 2 * 4);
  int*    offs     = (int*)  alloc(64);
  int*    cnts     = (int*)  alloc(64);
  if (off > ws_size) {
    fprintf(stderr, "ATHENA: WORKSPACE TOO SMALL: need %zu bytes, have %zu\n", off, ws_size);
    return;
  }

  __bf16* wt_s = wbuf;
  __bf16* wt_r = wbuf + (size_t)ES_ * H_ * C_;

  GP p;
  p.xns = xns; p.xnr = xnr; p.hids = hids; p.hidr = hidr;
  p.wts = wt_s; p.wtr = wt_r;
  p.b1s = b1s; p.b1r = b1r; p.b2s = b2s; p.b2r = b2r;
  p.hidws = hids; p.hidwr = hidr; p.out = out;
  p.listTok = listTok; p.listGate = listGate; p.offs = offs; p.cnts = cnts;

  k_init<<<dim3(NTOK * C_ / 1024), dim3(256), 0, stream>>>(u, out);
  k_prep<<<dim3(NTOK), dim3(256), 0, stream>>>(u, gs, gr, cent, xns, xnr, tki, tkg);
  k_build<<<dim3(1), dim3(256), 0, stream>>>(tki, tkg, listTok, listGate, offs, cnts);

  // W1 [E][C][H] -> bf16 [E*H][C]
  k_convT<<<dim3(H_/64, C_/64, ES_), dim3(256), 0, stream>>>(W1s, wt_s, C_, H_);
  k_convT<<<dim3(H_/64, C_/64, ER_), dim3(256), 0, stream>>>(W1r, wt_r, C_, H_);

  // fused GEMM1: z = {2 shared groups, 8 routed experts}; n=32, m=16
  k_gemm<1><<<dim3(32, 16, ES_ + ER_), dim3(256), 0, stream>>>(p);

  // W2: shared stacked [2H][C] -> [C][2H]; routed per-expert [H][C] -> [C][H]
  k_convT<<<dim3(C_/64, (ES_*H_)/64, 1), dim3(256), 0, stream>>>(W2s, wt_s, ES_*H_, C_);
  k_convT<<<dim3(C_/64, H_/64, ER_), dim3(256), 0, stream>>>(W2r, wt_r, H_, C_);

  // fused GEMM2: z = {2 shared kc, 16 routed (e,kc)}; n=8, m=16; atomic into out
  k_gemm<2><<<dim3(8, 16, 2 + ER_*2), dim3(256), 0, stream>>>(p);
}